// Round 9
// baseline (76.655 us; speedup 1.0000x reference)
//
#include <hip/hip_runtime.h>
#include <hip/hip_bf16.h>

#define BATCH 8
#define NDIM 2048
#define FDIM 256
#define CH 32   // row-chunks for column-sum partials (64 rows each)

typedef float f32x4 __attribute__((ext_vector_type(4)));
typedef short bf16x8 __attribute__((ext_vector_type(8)));
typedef short bf16x4 __attribute__((ext_vector_type(4)));

// hardware RNE convert (lowers to v_cvt_pk_bf16_f32 when paired)
__device__ __forceinline__ short f2bf(float f) {
  __hip_bfloat16 h = __float2bfloat16(f);
  short s;
  __builtin_memcpy(&s, &h, 2);
  return s;
}

__device__ __forceinline__ void gload_lds16(const void* g, void* l) {
  __builtin_amdgcn_global_load_lds(
      (const __attribute__((address_space(1))) void*)g,
      (__attribute__((address_space(3))) void*)l, 16, 0, 0);
}

// ---- Kernel 1: partial column sums of adj ----
__global__ __launch_bounds__(256) void k_colsum(const float* __restrict__ adj,
                                                float* __restrict__ part) {
  int bid = blockIdx.x;
  int cb = bid & 1;
  int ch = (bid >> 1) & (CH - 1);
  int b = bid >> 6;
  int col = cb * 1024 + threadIdx.x * 4;
  const float* p = adj + (size_t)b * NDIM * NDIM + (size_t)(ch * 64) * NDIM + col;
  f32x4 acc = {0.f, 0.f, 0.f, 0.f};
#pragma unroll 8
  for (int i = 0; i < 64; ++i) acc += *(const f32x4*)(p + (size_t)i * NDIM);
  *(f32x4*)(part + (size_t)(b * CH + ch) * NDIM + col) = acc;
}

// ---- Kernel 2 (merged): blocks 0..63 -> d = rsqrt(colsum); 64..79 -> Wt ----
__global__ __launch_bounds__(256) void k_small(const float* __restrict__ part,
                                               float* __restrict__ dnorm,
                                               const float* __restrict__ w,
                                               short* __restrict__ wt) {
  int t = threadIdx.x;
  if (blockIdx.x < 64) {
    int idx = blockIdx.x * 256 + t;  // b*NDIM + j
    int b = idx >> 11, j = idx & (NDIM - 1);
    float s = 0.f;
#pragma unroll
    for (int c = 0; c < CH; ++c) s += part[(size_t)(b * CH + c) * NDIM + j];
    dnorm[idx] = rsqrtf(s);
  } else {
    __shared__ float tile[64][65];
    int bb = blockIdx.x - 64;
    int bx = bb & 3, by = bb >> 2;
    int f0 = by * 64, o0 = bx * 64;
    int c4 = 4 * (t & 15);
#pragma unroll
    for (int q = 0; q < 4; ++q) {
      int r = (t >> 4) + 16 * q;
      f32x4 v = *(const f32x4*)(w + (size_t)(f0 + r) * FDIM + o0 + c4);
#pragma unroll
      for (int i = 0; i < 4; ++i) tile[r][c4 + i] = v[i];
    }
    __syncthreads();
#pragma unroll
    for (int q = 0; q < 4; ++q) {
      int r = (t >> 4) + 16 * q;
      bf16x4 pk;
#pragma unroll
      for (int i = 0; i < 4; ++i) pk[i] = f2bf(tile[c4 + i][r]);
      *(bf16x4*)(wt + (size_t)(o0 + r) * FDIM + f0 + c4) = pk;
    }
  }
}

// ---- Kernel 3: St[b][o][m] = bf16(d[b][m] * (X @ W)[m][o]) ----
__global__ __launch_bounds__(256) void k_support(const float* __restrict__ in,
                                                 const short* __restrict__ wt,
                                                 const float* __restrict__ dnorm,
                                                 short* __restrict__ st) {
  __shared__ short Al[64 * 32];
  __shared__ short Bl[256 * 32];
  int t = threadIdx.x, lane = t & 63, w = t >> 6;
  int b = blockIdx.x >> 5;
  int m0 = (blockIdx.x & 31) * 64;
  const float* inb = in + ((size_t)b * NDIM + m0) * FDIM;

  f32x4 acc[4][4];
#pragma unroll
  for (int m = 0; m < 4; ++m)
#pragma unroll
    for (int n = 0; n < 4; ++n) acc[m][n] = {0.f, 0.f, 0.f, 0.f};

  int ar = t >> 2, ac = t & 3;
  for (int it = 0; it < 8; ++it) {
    int k0 = it * 32;
    {
      f32x4 v0 = *(const f32x4*)(inb + (size_t)ar * FDIM + k0 + 8 * ac);
      f32x4 v1 = *(const f32x4*)(inb + (size_t)ar * FDIM + k0 + 8 * ac + 4);
      bf16x8 p;
#pragma unroll
      for (int i = 0; i < 4; ++i) { p[i] = f2bf(v0[i]); p[4 + i] = f2bf(v1[i]); }
      *(bf16x8*)&Al[ar * 32 + 8 * ac] = p;
    }
#pragma unroll
    for (int i = 0; i < 4; ++i) {
      int ss = i * 256 + t;
      int o = ss >> 2, c = ss & 3;
      gload_lds16(wt + (size_t)o * FDIM + k0 + 8 * c, &Bl[ss * 8]);
    }
    __syncthreads();
    bf16x8 af[4], bf[4];
#pragma unroll
    for (int m = 0; m < 4; ++m)
      af[m] = *(const bf16x8*)&Al[(16 * m + (lane & 15)) * 32 + (lane >> 4) * 8];
#pragma unroll
    for (int n = 0; n < 4; ++n)
      bf[n] = *(const bf16x8*)&Bl[(64 * w + 16 * n + (lane & 15)) * 32 + (lane >> 4) * 8];
#pragma unroll
    for (int m = 0; m < 4; ++m)
#pragma unroll
      for (int n = 0; n < 4; ++n)
        acc[m][n] = __builtin_amdgcn_mfma_f32_16x16x32_bf16(af[m], bf[n], acc[m][n], 0, 0, 0);
    __syncthreads();
  }
#pragma unroll
  for (int m = 0; m < 4; ++m) {
    int row = m0 + 16 * m + ((lane >> 4) << 2);
    float dm[4];
#pragma unroll
    for (int j = 0; j < 4; ++j) dm[j] = dnorm[b * NDIM + row + j];
#pragma unroll
    for (int n = 0; n < 4; ++n) {
      int col = 64 * w + 16 * n + (lane & 15);
      bf16x4 pk;
#pragma unroll
      for (int j = 0; j < 4; ++j) pk[j] = f2bf(acc[m][n][j] * dm[j]);
      *(bf16x4*)(st + ((size_t)(b * FDIM + col)) * NDIM + row) = pk;
    }
  }
}

// ---- Kernel 4: out = d_n * (adj @ St^T) + bias ----
// 512 blocks x 512 threads (8 waves, 2Mx4N), BM=64, BN=128, BK=64.
// 2 blocks/CU (64 KB LDS, launch_bounds(512,4)): co-resident block covers
// rendezvous stalls. Double-buffered, counted vmcnt(4) (4 gll/tile, depth-1).
// A swizzle at 32B granule: g ^= row&7 (bijective, 2-way residue = free).
__global__ __launch_bounds__(512, 4) void k_main(const float* __restrict__ adj,
                                                 const short* __restrict__ st,
                                                 const float* __restrict__ dnorm,
                                                 const float* __restrict__ bias,
                                                 float* __restrict__ out) {
  __shared__ float Alf[2][64 * 64];   // 2 x 16 KB (f32 A tiles)
  __shared__ short Bl[2][128 * 64];   // 2 x 16 KB (bf16 B tiles)
  int t = threadIdx.x, lane = t & 63, w = t >> 6;
  int wm = w & 1, wn = w >> 1;
  int b = blockIdx.x & 7;              // batch <-> XCD
  int rc = blockIdx.x >> 3;
  int colh = rc & 1;                   // which 128-col half of F
  int n0 = (rc >> 1) * 64;             // M row-tile
  const float* ab = adj + ((size_t)b * NDIM + n0) * NDIM;
  const short* stb = st + (size_t)b * FDIM * NDIM + (size_t)(colh * 128) * NDIM;

  // A staging: 1024 slots of 16B; slot s -> row=s>>4, chunk16 c=s&15.
  // LDS linear; source granule-swizzled: c_src = (((c>>1)^(row&7))<<1)|(c&1)
  int sA0 = t, sA1 = 512 + t;
  int rA0 = sA0 >> 4, cA0 = sA0 & 15;
  int rA1 = sA1 >> 4, cA1 = sA1 & 15;
  int cA0s = (((cA0 >> 1) ^ (rA0 & 7)) << 1) | (cA0 & 1);
  int cA1s = (((cA1 >> 1) ^ (rA1 & 7)) << 1) | (cA1 & 1);
  const float* aS0 = ab + (size_t)rA0 * NDIM + cA0s * 4;
  const float* aS1 = ab + (size_t)rA1 * NDIM + cA1s * 4;
  // B staging: 1024 slots of 16B; slot s -> row=s>>3, chunk c=s&7.
  // source chunk-swizzled: c_src = c ^ (row&7)
  int sB0 = t, sB1 = 512 + t;
  int rB0 = sB0 >> 3, cB0 = (sB0 & 7) ^ (rB0 & 7);
  int rB1 = sB1 >> 3, cB1 = (sB1 & 7) ^ (rB1 & 7);
  const short* bS0 = stb + (size_t)rB0 * NDIM + cB0 * 8;
  const short* bS1 = stb + (size_t)rB1 * NDIM + cB1 * 8;

  f32x4 acc[2][2];
#pragma unroll
  for (int m = 0; m < 2; ++m)
#pragma unroll
    for (int n = 0; n < 2; ++n) acc[m][n] = {0.f, 0.f, 0.f, 0.f};

  int lr = lane & 15, kg = lane >> 4, sw = lane & 7;

  auto stage = [&](int k, int bp) {
    size_t ko = (size_t)k * 64;
    gload_lds16(aS0 + ko, &Alf[bp][sA0 * 4]);
    gload_lds16(aS1 + ko, &Alf[bp][sA1 * 4]);
    gload_lds16(bS0 + ko, &Bl[bp][sB0 * 8]);
    gload_lds16(bS1 + ko, &Bl[bp][sB1 * 8]);
  };

  auto body = [&](int it, int bc, bool last) {
    if (!last) {
      stage(it + 1, bc ^ 1);
      asm volatile("s_waitcnt vmcnt(4)" ::: "memory");
    } else {
      asm volatile("s_waitcnt vmcnt(0)" ::: "memory");
    }
    __builtin_amdgcn_s_barrier();
    asm volatile("" ::: "memory");
    __builtin_amdgcn_sched_barrier(0);
#pragma unroll
    for (int h = 0; h < 2; ++h) {
      int gk = h * 4 + kg;              // 32B granule 0..7 (k-offset gk*8)
      int gsw = (gk ^ sw) * 8;
      bf16x8 af[2];
#pragma unroll
      for (int mf = 0; mf < 2; ++mf) {
        const float* ap = &Alf[bc][(wm * 32 + mf * 16 + lr) * 64 + gsw];
        f32x4 lo = *(const f32x4*)ap;
        f32x4 hi = *(const f32x4*)(ap + 4);
#pragma unroll
        for (int j = 0; j < 4; ++j) { af[mf][j] = f2bf(lo[j]); af[mf][4 + j] = f2bf(hi[j]); }
      }
      bf16x8 bv0 = *(const bf16x8*)&Bl[bc][(wn * 32 + lr) * 64 + gsw];
      bf16x8 bv1 = *(const bf16x8*)&Bl[bc][(wn * 32 + 16 + lr) * 64 + gsw];
      acc[0][0] = __builtin_amdgcn_mfma_f32_16x16x32_bf16(af[0], bv0, acc[0][0], 0, 0, 0);
      acc[0][1] = __builtin_amdgcn_mfma_f32_16x16x32_bf16(af[0], bv1, acc[0][1], 0, 0, 0);
      acc[1][0] = __builtin_amdgcn_mfma_f32_16x16x32_bf16(af[1], bv0, acc[1][0], 0, 0, 0);
      acc[1][1] = __builtin_amdgcn_mfma_f32_16x16x32_bf16(af[1], bv1, acc[1][1], 0, 0, 0);
    }
    asm volatile("s_waitcnt lgkmcnt(0)" ::: "memory");
    __builtin_amdgcn_s_barrier();
    asm volatile("" ::: "memory");
  };

  stage(0, 0);
  for (int it = 0; it < 31; ++it) body(it, it & 1, false);
  body(31, 1, true);

  // epilogue: out[b][row][col] = d_n[row]*acc + bias[col]
#pragma unroll
  for (int mf = 0; mf < 2; ++mf) {
    int row = n0 + wm * 32 + mf * 16 + kg * 4;
    f32x4 dr = *(const f32x4*)&dnorm[b * NDIM + row];
#pragma unroll
    for (int nf = 0; nf < 2; ++nf) {
      int col = colh * 128 + wn * 32 + nf * 16 + lr;
      float bv = bias[col];
      float* op = out + ((size_t)b * NDIM + row) * FDIM + col;
#pragma unroll
      for (int j = 0; j < 4; ++j) op[(size_t)j * FDIM] = dr[j] * acc[mf][nf][j] + bv;
    }
  }
}

extern "C" void kernel_launch(void* const* d_in, const int* in_sizes, int n_in,
                              void* d_out, int out_size, void* d_ws, size_t ws_size,
                              hipStream_t stream) {
  (void)in_sizes; (void)n_in; (void)out_size; (void)ws_size;
  const float* input = (const float*)d_in[0];
  const float* adj = (const float*)d_in[1];
  const float* weight = (const float*)d_in[2];
  const float* bias = (const float*)d_in[3];
  float* out = (float*)d_out;

  char* ws = (char*)d_ws;
  short* st = (short*)ws;                                       // 8 MB  (bf16 S^T)
  float* dnorm = (float*)(ws + 8ull * 1024 * 1024);             // 64 KB
  float* part = (float*)(ws + 8ull * 1024 * 1024 + 65536);      // 2 MB
  short* wt = (short*)(ws + 8ull * 1024 * 1024 + 65536 + 2ull * 1024 * 1024);  // 128 KB

  k_colsum<<<dim3(BATCH * CH * 2), dim3(256), 0, stream>>>(adj, part);
  k_small<<<dim3(80), dim3(256), 0, stream>>>(part, dnorm, weight, wt);
  k_support<<<dim3(BATCH * (NDIM / 64)), dim3(256), 0, stream>>>(input, wt, dnorm, st);
  k_main<<<dim3(BATCH * (NDIM / 32)), dim3(512), 0, stream>>>(adj, st, dnorm, bias, out);
}